// Round 1
// baseline (78.754 us; speedup 1.0000x reference)
//
#include <hip/hip_runtime.h>
#include <stdint.h>

// Problem constants: B=16, R=400, H=8, Q=64, D=1200
// M = B*R = 6400, N = H*Q*2 = 1024 (q | k concat), K padded 1200 -> 1216
#define DPAD 1216
#define MROWS 6400

typedef float f32x4 __attribute__((ext_vector_type(4)));
typedef __bf16 bf16x8 __attribute__((ext_vector_type(8)));
typedef __attribute__((address_space(3))) uint8_t as3_u8;
typedef __attribute__((address_space(1))) uint8_t as1_u8;

__device__ __forceinline__ void gload_lds16(const void* g, void* l) {
  __builtin_amdgcn_global_load_lds((as1_u8*)g, (as3_u8*)l, 16, 0, 0);
}

// ---------------- Kernel 1: x fp32 -> bf16, pad K 1200->1216 ----------------
// grid: 6400 rows * 152 chunks / 256 = 3800 blocks
__global__ void cvt_x(const float* __restrict__ x, __bf16* __restrict__ xb) {
  const int id = blockIdx.x * 256 + threadIdx.x;   // < 972800 exactly
  const int row = id / 152;
  const int c = id - row * 152;
  const int col = c * 8;
  bf16x8 v;
  if (col < 1200) {
    const float4* p = (const float4*)(x + row * 1200 + col);
    const float4 f0 = p[0], f1 = p[1];
    v[0] = (__bf16)f0.x; v[1] = (__bf16)f0.y; v[2] = (__bf16)f0.z; v[3] = (__bf16)f0.w;
    v[4] = (__bf16)f1.x; v[5] = (__bf16)f1.y; v[6] = (__bf16)f1.z; v[7] = (__bf16)f1.w;
  } else {
#pragma unroll
    for (int i = 0; i < 8; ++i) v[i] = (__bf16)0.0f;
  }
  *(bf16x8*)(xb + (size_t)row * DPAD + col) = v;
}

// ------------- Kernel 2: Wq,Wk fp32 [1200][512] -> Wt bf16 [1024][1216] -----
// Wt[n][k] = W[k][n] (transposed, q rows 0..511, k rows 512..1023), K padded.
// grid: 1024 * 152 / 256 = 608 blocks
__global__ void cvt_w(const float* __restrict__ wq, const float* __restrict__ wk,
                      __bf16* __restrict__ wt) {
  const int id = blockIdx.x * 256 + threadIdx.x;   // < 155648 exactly
  const int n = id / 152;
  const int c = id - n * 152;
  const int k0 = c * 8;
  const float* src = (n < 512) ? (wq + n) : (wk + (n - 512));
  bf16x8 v;
#pragma unroll
  for (int i = 0; i < 8; ++i) {
    const int k = k0 + i;
    v[i] = (k < 1200) ? (__bf16)src[(size_t)k * 512] : (__bf16)0.0f;
  }
  *(bf16x8*)(wt + (size_t)n * DPAD + k0) = v;
}

// ---------------- Kernel 3: GEMM qk[6400][1024] = xb @ Wt^T + bias ----------
// m97 structure: 128x128 tile, BK=32, 256 threads (4 waves, 2x2), 16x16x32 MFMA
__global__ __launch_bounds__(256) void gemm_qk(const __bf16* __restrict__ xb,
                                               const __bf16* __restrict__ wt,
                                               const float* __restrict__ bq,
                                               const float* __restrict__ bk,
                                               __bf16* __restrict__ qk) {
  __shared__ __bf16 As[128 * 32];   // 8 KB
  __shared__ __bf16 Bs[128 * 32];   // 8 KB
  const int m0 = blockIdx.x * 128;  // 50 tiles
  const int n0 = blockIdx.y * 128;  // 8 tiles
  const int t = threadIdx.x;
  const int lane = t & 63;
  const int wid = t >> 6;
  const int wr = wid >> 1, wc = wid & 1;
  const int lrow = lane & 15, lk = lane >> 4;

  f32x4 acc[4][4];
#pragma unroll
  for (int i = 0; i < 4; ++i)
#pragma unroll
    for (int j = 0; j < 4; ++j) acc[i][j] = (f32x4){0.f, 0.f, 0.f, 0.f};

  for (int k0 = 0; k0 < DPAD; k0 += 32) {
#pragma unroll
    for (int it = 0; it < 2; ++it) {
      const int id = it * 256 + t;        // 0..511 chunk id
      const int row = id >> 2, cc = id & 3;
      gload_lds16(xb + (size_t)(m0 + row) * DPAD + k0 + cc * 8, (char*)As + id * 16);
      gload_lds16(wt + (size_t)(n0 + row) * DPAD + k0 + cc * 8, (char*)Bs + id * 16);
    }
    __syncthreads();
    bf16x8 a[4], bfr[4];
#pragma unroll
    for (int i = 0; i < 4; ++i)
      a[i] = *(const bf16x8*)(As + (wr * 64 + i * 16 + lrow) * 32 + lk * 8);
#pragma unroll
    for (int i = 0; i < 4; ++i)
      bfr[i] = *(const bf16x8*)(Bs + (wc * 64 + i * 16 + lrow) * 32 + lk * 8);
#pragma unroll
    for (int mi = 0; mi < 4; ++mi)
#pragma unroll
      for (int ni = 0; ni < 4; ++ni)
        acc[mi][ni] = __builtin_amdgcn_mfma_f32_16x16x32_bf16(a[mi], bfr[ni], acc[mi][ni], 0, 0, 0);
    __syncthreads();
  }
  // epilogue: D layout col=lane&15, row=(lane>>4)*4+r  [m89-verified]
#pragma unroll
  for (int mi = 0; mi < 4; ++mi) {
#pragma unroll
    for (int ni = 0; ni < 4; ++ni) {
      const int gr0 = m0 + wr * 64 + mi * 16 + lk * 4;
      const int gc = n0 + wc * 64 + ni * 16 + lrow;
      const float bias = (gc < 512) ? bq[gc] : bk[gc - 512];
#pragma unroll
      for (int r = 0; r < 4; ++r)
        qk[(size_t)(gr0 + r) * 1024 + gc] = (__bf16)(acc[mi][ni][r] + bias);
    }
  }
}

// ---------------- Kernel 4: per (b,h) attention scores + softmax + relu -----
// grid: (25 row-tiles of 16, 128 bh). Block 256 threads = 4 waves.
__global__ __launch_bounds__(256) void attn(const __bf16* __restrict__ qk,
                                            const float* __restrict__ thr_p,
                                            float* __restrict__ out) {
  __shared__ __bf16 klds[400 * 64];   // 51200 B, XOR-swizzled chunks
  __shared__ __bf16 qlds[16 * 64];    // 2048 B, linear
  __shared__ float slds[16 * 404];    // 25856 B (pad 404)
  const int bh = blockIdx.y;
  const int b = bh >> 3;
  const int h = bh & 7;
  const int r0 = blockIdx.x * 16;
  const int t = threadIdx.x;
  const int lane = t & 63;
  const int wid = t >> 6;
  const __bf16* kbase = qk + (size_t)(b * 400) * 1024 + 512 + h * 64;
  const __bf16* qbase = qk + (size_t)(b * 400 + r0) * 1024 + h * 64;

  // stage k[400][64]: 3200 16B chunks. LDS dest linear; swizzle the GLOBAL
  // source (m173 pattern): slot (row,c) holds global chunk c^(row&7).
#pragma unroll
  for (int it = 0; it < 12; ++it) {
    const int id = it * 256 + t;
    const int row = id >> 3, c = id & 7;
    const int csw = c ^ (row & 7);
    gload_lds16(kbase + (size_t)row * 1024 + csw * 8, (char*)klds + id * 16);
  }
  if (wid < 2) {  // wave-uniform tail: chunks 3072..3199 + q staging
    const int id = 3072 + t;
    const int row = id >> 3, c = id & 7;
    const int csw = c ^ (row & 7);
    gload_lds16(kbase + (size_t)row * 1024 + csw * 8, (char*)klds + id * 16);
    const int qrow = t >> 3, qc = t & 7;
    gload_lds16(qbase + (size_t)qrow * 1024 + qc * 8, (char*)qlds + t * 16);
  }
  __syncthreads();

  const int lrow = lane & 15, lk = lane >> 4;
  bf16x8 aq[2];
#pragma unroll
  for (int kk = 0; kk < 2; ++kk)
    aq[kk] = *(const bf16x8*)(qlds + lrow * 64 + kk * 32 + lk * 8);

  // S[i][j] = q_i . k_j / 64 ; wave w handles col-tiles jt = w, w+4, ...
  for (int jt = wid; jt < 25; jt += 4) {
    f32x4 acc = (f32x4){0.f, 0.f, 0.f, 0.f};
#pragma unroll
    for (int kk = 0; kk < 2; ++kk) {
      const int krow = jt * 16 + lrow;
      const int cwant = kk * 4 + lk;
      const int csw = cwant ^ (krow & 7);
      const bf16x8 bkf = *(const bf16x8*)(klds + krow * 64 + csw * 8);
      acc = __builtin_amdgcn_mfma_f32_16x16x32_bf16(aq[kk], bkf, acc, 0, 0, 0);
    }
    const int scol = jt * 16 + lrow;
#pragma unroll
    for (int r = 0; r < 4; ++r)
      slds[(lk * 4 + r) * 404 + scol] = acc[r] * 0.015625f;  // /Q
  }
  __syncthreads();

  // softmax over 400 cols; 16 threads per row (lanes 0..15 of a 16-group)
  const int row = t >> 4, c = t & 15;
  const float thr = thr_p[0] * 0.01f;
  float vals[25];
  float m = -1e30f;
#pragma unroll
  for (int j = 0; j < 25; ++j) {
    vals[j] = slds[row * 404 + j * 16 + c];
    m = fmaxf(m, vals[j]);
  }
#pragma unroll
  for (int off = 8; off >= 1; off >>= 1) m = fmaxf(m, __shfl_xor(m, off, 16));
  float sum = 0.f;
#pragma unroll
  for (int j = 0; j < 25; ++j) {
    vals[j] = __expf(vals[j] - m);
    sum += vals[j];
  }
#pragma unroll
  for (int off = 8; off >= 1; off >>= 1) sum += __shfl_xor(sum, off, 16);
  const float inv = 1.0f / sum;
  float* orow = out + ((size_t)bh * 400 + r0 + row) * 400;
#pragma unroll
  for (int j = 0; j < 25; ++j) {
    const float p = vals[j] * inv - thr;
    orow[j * 16 + c] = p > 0.f ? p : 0.f;
  }
}

// ---------------------------------------------------------------------------
extern "C" void kernel_launch(void* const* d_in, const int* in_sizes, int n_in,
                              void* d_out, int out_size, void* d_ws, size_t ws_size,
                              hipStream_t stream) {
  const float* x   = (const float*)d_in[0];
  const float* Wq  = (const float*)d_in[1];
  const float* bq  = (const float*)d_in[2];
  const float* Wk  = (const float*)d_in[3];
  const float* bk  = (const float*)d_in[4];
  const float* thr = (const float*)d_in[5];
  char* ws = (char*)d_ws;
  __bf16* xb = (__bf16*)ws;                   // 6400*1216*2 = 15,564,800 B
  __bf16* wt = (__bf16*)(ws + 15564800);      // 1024*1216*2 =  2,490,368 B
  __bf16* qk = (__bf16*)(ws + 18055168);      // 6400*1024*2 = 13,107,200 B
  float* out = (float*)d_out;

  cvt_x<<<dim3(3800), dim3(256), 0, stream>>>(x, xb);
  cvt_w<<<dim3(608), dim3(256), 0, stream>>>(Wq, Wk, wt);
  gemm_qk<<<dim3(50, 8), dim3(256), 0, stream>>>(xb, wt, bq, bk, qk);
  attn<<<dim3(25, 128), dim3(256), 0, stream>>>(qk, thr, out);
}